// Round 14
// baseline (89.850 us; speedup 1.0000x reference)
//
#include <hip/hip_runtime.h>

typedef __attribute__((ext_vector_type(8))) __bf16 bf16x8;
typedef __attribute__((ext_vector_type(4))) float f32x4;
typedef __attribute__((ext_vector_type(2))) float f32x2;

#define DI 512
#define DO 512
#define XROW (128 * DI)
#define OROW (128 * DO)
#define BK 32
#define BBUF 16384           // B buffer: bf16 [256 o][32 k] = 16 KB, x2

#define LGKM0()  asm volatile("s_waitcnt lgkmcnt(0)" ::: "memory")
#define SBAR()   __builtin_amdgcn_s_barrier()
#define SCHED0() __builtin_amdgcn_sched_barrier(0)

__global__ __launch_bounds__(512, 4)
void nlinear_mfma(const float* __restrict__ xp, const float* __restrict__ wp,
                  const float* __restrict__ bp, float* __restrict__ op) {
  // XCD swizzle (R10-proven): 512 blocks, 64 per XCD; one n's 4 tiles together
  int blk = blockIdx.x;
  int L = ((blk & 7) << 6) + (blk >> 3);
  int n = L >> 2, mt = (L >> 1) & 1, ot = L & 1;
  int mBase = mt << 7, oBase = ot << 8;      // block tile: 128m x 256o

  __shared__ char lds[2 * BBUF];             // B only: 32 KB

  int tid = threadIdx.x, lane = tid & 63, wid = tid >> 6;
  int wm = (wid >> 2) << 6, wn = (wid & 3) << 6;   // wave tile 64m x 64o
  int l16 = lane & 15, l4 = lane >> 4;

  // A fragments DIRECT from global (no LDS): lane reads
  // x[mBase+wm+i*16+l16][kt*32 + l4*8 .. +8] as 2 x dwordx4. Per row the
  // 4 l4-chunks are 128B contiguous; x-tile is L2-resident (512 KB/n/XCD).
  const float* aB = xp + (size_t)(mBase + wm + l16) * XROW + n * DI + l4 * 8;

  // B staging (R10-proven, unchanged): thread t -> o-pair {2*(t&127), +1},
  // k-range kq*8..+8; 8 x f32x2 loads, 2 x b128 k-contiguous swizzled writes.
  int bo2 = (tid & 127) << 1, kq = tid >> 7;
  const float* bSrc = wp + ((size_t)n * DI + (kq << 3)) * DO + oBase + bo2;
  int bWr0 = (bo2)     * 64 + ((kq ^ ((bo2 >> 1) & 3)) << 4);
  int bWr1 = (bo2 + 1) * 64 + ((kq ^ ((bo2 >> 1) & 3)) << 4);

  f32x2 bRv[8];
  auto loadB = [&](int kt) {
    #pragma unroll
    for (int j = 0; j < 8; ++j)
      bRv[j] = *(const f32x2*)(bSrc + (size_t)(kt * BK + j) * DO);
  };
  auto writeB = [&](int bufOff) {
    bf16x8 v0, v1;
    #pragma unroll
    for (int j = 0; j < 8; ++j) { v0[j] = (__bf16)bRv[j].x; v1[j] = (__bf16)bRv[j].y; }
    *(bf16x8*)(lds + bufOff + bWr0) = v0;
    *(bf16x8*)(lds + bufOff + bWr1) = v1;
  };

  f32x4 acc[4][4];
  #pragma unroll
  for (int i = 0; i < 4; ++i)
    #pragma unroll
    for (int j = 0; j < 4; ++j)
      acc[i][j] = f32x4{0.f, 0.f, 0.f, 0.f};

  bf16x8 af[4];
  auto computeJ = [&](int bufOff, int j) {
    int row = wn + j * 16 + l16;
    int slot = l4 ^ ((row >> 1) & 3);
    bf16x8 bfr = *(const bf16x8*)(lds + bufOff + row * 64 + slot * 16);
    #pragma unroll
    for (int i = 0; i < 4; ++i)
      acc[i][j] = __builtin_amdgcn_mfma_f32_16x16x32_bf16(af[i], bfr, acc[i][j], 0, 0, 0);
  };

  float bi[4];
  #pragma unroll
  for (int j = 0; j < 4; ++j)
    bi[j] = bp[n * DO + oBase + wn + j * 16 + l16];

  // ---- prologue: B0 staged, B1 in flight across the barrier ----
  loadB(0);
  writeB(0);                 // one-time full wait on B0
  loadB(1);
  SCHED0(); LGKM0(); SBAR(); SCHED0();

  // iter kt: A(kt) loads+cvt (first cvt-wait also retires the aged B(kt+1));
  // J0,J1; writeB(kt+1) [no extra wait]; issue B(kt+2) — stays in flight
  // across J2,J3 + barrier (lgkm-only, no vmcnt drain).
  for (int kt = 0; kt < 16; ++kt) {
    int curOff = (kt & 1) * BBUF;
    int nxtOff = curOff ^ BBUF;

    #pragma unroll
    for (int i = 0; i < 4; ++i) {
      const float* ap = aB + i * (16 * XROW) + kt * BK;
      f32x4 lo = *(const f32x4*)(ap);
      f32x4 hi = *(const f32x4*)(ap + 4);
      af[i][0] = (__bf16)lo.x; af[i][1] = (__bf16)lo.y;
      af[i][2] = (__bf16)lo.z; af[i][3] = (__bf16)lo.w;
      af[i][4] = (__bf16)hi.x; af[i][5] = (__bf16)hi.y;
      af[i][6] = (__bf16)hi.z; af[i][7] = (__bf16)hi.w;
    }

    computeJ(curOff, 0);
    computeJ(curOff, 1);
    if (kt < 15) {
      writeB(nxtOff);        // B(kt+1) regs -> LDS (already arrived)
      if (kt < 14) loadB(kt + 2);   // 8 VMEM in flight across barrier
      SCHED0();
    }
    computeJ(curOff, 2);
    computeJ(curOff, 3);
    if (kt < 15) {
      SCHED0(); LGKM0(); SBAR(); SCHED0();
    }
  }

  // epilogue: D layout col = lane&15, row = (lane>>4)*4 + r (m89-verified)
  #pragma unroll
  for (int i = 0; i < 4; ++i) {
    #pragma unroll
    for (int j = 0; j < 4; ++j) {
      #pragma unroll
      for (int r = 0; r < 4; ++r) {
        int m = mBase + wm + i * 16 + l4 * 4 + r;
        int o = oBase + wn + j * 16 + l16;
        op[(size_t)m * OROW + n * DO + o] = acc[i][j][r] + bi[j];
      }
    }
  }
}

extern "C" void kernel_launch(void* const* d_in, const int* in_sizes, int n_in,
                              void* d_out, int out_size, void* d_ws, size_t ws_size,
                              hipStream_t stream) {
  const float* x = (const float*)d_in[0];
  const float* w = (const float*)d_in[1];
  const float* b = (const float*)d_in[2];
  float* o = (float*)d_out;
  hipLaunchKernelGGL(nlinear_mfma, dim3(512), dim3(512), 0, stream, x, w, b, o);
}

// Round 15
// 46.581 us; speedup vs baseline: 1.9289x; 1.9289x over previous
//
#include <hip/hip_runtime.h>

typedef __attribute__((ext_vector_type(8))) __bf16 bf16x8;
typedef __attribute__((ext_vector_type(4))) float f32x4;
typedef __attribute__((ext_vector_type(2))) float f32x2;

#define DI 512
#define DO 512
#define XROW (128 * DI)
#define OROW (128 * DO)
#define BK 32
#define BOFF 16384          // A: fp32 [128][32] = 16 KB | B: bf16 [256][32] = 16 KB
#define BUFSZ 32768

#define VMCNT(n) asm volatile("s_waitcnt vmcnt(" #n ")" ::: "memory")
#define LGKM0()  asm volatile("s_waitcnt lgkmcnt(0)" ::: "memory")
#define SBAR()   __builtin_amdgcn_s_barrier()
#define SCHED0() __builtin_amdgcn_sched_barrier(0)
#define PRIO1()  __builtin_amdgcn_s_setprio(1)
#define PRIO0()  __builtin_amdgcn_s_setprio(0)

// This kernel is R10 (45.5 us, best-known) byte-identical EXCEPT for T5
// s_setprio around the two MFMA clusters. R11/R12/R13 all regressed by
// perturbing registers/structure; setprio is 4 SALU instrs, 0 regs.

__global__ __launch_bounds__(512, 4)
void nlinear_mfma(const float* __restrict__ xp, const float* __restrict__ wp,
                  const float* __restrict__ bp, float* __restrict__ op) {
  // XCD swizzle: 512 blocks, 64 per XCD; the 4 tiles of one n stay together
  int blk = blockIdx.x;
  int L = ((blk & 7) << 6) + (blk >> 3);
  int n = L >> 2, mt = (L >> 1) & 1, ot = L & 1;
  int mBase = mt << 7, oBase = ot << 8;      // block tile: 128m x 256o

  __shared__ char lds[2 * BUFSZ];            // 64 KB

  int tid = threadIdx.x, lane = tid & 63, wid = tid >> 6;
  int wm = (wid >> 2) << 6, wn = (wid & 3) << 6;   // wave tile 64m x 64o
  int l16 = lane & 15, l4 = lane >> 4;

  // A DMA (R8-R10 proven): wave w rows w*16..+16, 2 instrs x 1KB; source
  // pre-swizzled slot g = (lane&7) ^ ((row>>1)&7), LDS dest linear (rule #21).
  unsigned aOff[2];
  #pragma unroll
  for (int i = 0; i < 2; ++i) {
    int r0 = (wid << 4) + (i << 3);
    int row = r0 + (lane >> 3);
    int g = (lane & 7) ^ ((row >> 1) & 7);
    aOff[i] = (unsigned)(((mBase + row) * XROW + n * DI) * 4 + g * 16);
  }
  auto gloadA = [&](int bufOff, int kt) {
    #pragma unroll
    for (int i = 0; i < 2; ++i) {
      int r0 = (wid << 4) + (i << 3);
      __builtin_amdgcn_global_load_lds(
          (const __attribute__((address_space(1))) void*)
              ((const char*)xp + aOff[i] + (unsigned)(kt * 128)),
          (__attribute__((address_space(3))) void*)(lds + bufOff + r0 * 128),
          16, 0, 0);
    }
  };

  // B staging (R10-proven): thread t -> o-pair {2*(t&127), +1}, k-range
  // kq*8..+8; 8 x f32x2 loads (512B/wave per k-row), 2 x b128 writes.
  int bo2 = (tid & 127) << 1, kq = tid >> 7;
  const float* bSrc = wp + ((size_t)n * DI + (kq << 3)) * DO + oBase + bo2;
  int bWr0 = BOFF + (bo2)     * 64 + ((kq ^ ((bo2 >> 1) & 3)) << 4);
  int bWr1 = BOFF + (bo2 + 1) * 64 + ((kq ^ ((bo2 >> 1) & 3)) << 4);

  f32x2 bRv[8];
  auto loadB = [&](int kt) {
    #pragma unroll
    for (int j = 0; j < 8; ++j)
      bRv[j] = *(const f32x2*)(bSrc + (size_t)(kt * BK + j) * DO);
  };
  auto writeB = [&](int bufOff) {
    bf16x8 v0, v1;
    #pragma unroll
    for (int j = 0; j < 8; ++j) { v0[j] = (__bf16)bRv[j].x; v1[j] = (__bf16)bRv[j].y; }
    *(bf16x8*)(lds + bufOff + bWr0) = v0;
    *(bf16x8*)(lds + bufOff + bWr1) = v1;
  };

  f32x4 acc[4][4];
  #pragma unroll
  for (int i = 0; i < 4; ++i)
    #pragma unroll
    for (int j = 0; j < 4; ++j)
      acc[i][j] = f32x4{0.f, 0.f, 0.f, 0.f};

  bf16x8 af[4];
  auto loadAfrags = [&](int bufOff) {
    #pragma unroll
    for (int i = 0; i < 4; ++i) {
      int row = wm + i * 16 + l16;
      int v7 = (row >> 1) & 7;
      const char* rb = lds + bufOff + row * 128;
      f32x4 lo = *(const f32x4*)(rb + ((((l4 << 1))     ^ v7) << 4));
      f32x4 hi = *(const f32x4*)(rb + ((((l4 << 1) | 1) ^ v7) << 4));
      af[i][0] = (__bf16)lo.x; af[i][1] = (__bf16)lo.y;
      af[i][2] = (__bf16)lo.z; af[i][3] = (__bf16)lo.w;
      af[i][4] = (__bf16)hi.x; af[i][5] = (__bf16)hi.y;
      af[i][6] = (__bf16)hi.z; af[i][7] = (__bf16)hi.w;
    }
  };
  auto computeJ = [&](int bufOff, int j) {
    int row = wn + j * 16 + l16;
    int slot = l4 ^ ((row >> 1) & 3);
    bf16x8 bfr = *(const bf16x8*)(lds + bufOff + BOFF + row * 64 + slot * 16);
    #pragma unroll
    for (int i = 0; i < 4; ++i)
      acc[i][j] = __builtin_amdgcn_mfma_f32_16x16x32_bf16(af[i], bfr, acc[i][j], 0, 0, 0);
  };

  float bi[4];
  #pragma unroll
  for (int j = 0; j < 4; ++j)
    bi[j] = bp[n * DO + oBase + wn + j * 16 + l16];

  // ---- prologue: buf0 staged; B1 in flight across the barrier ----
  gloadA(0, 0);            // A0 (oldest)
  loadB(0);
  writeB(0);               // waits B0 regs -> in-order retires A0 too
  loadB(1);
  SCHED0(); LGKM0(); SBAR(); SCHED0();

  // iter kt: J0,J1 from cur; stage tile kt+1 (A-DMA + B-write) + issue
  // B(kt+2); J2,J3; VMCNT(8) retires A(kt+1), keeps B(kt+2) in flight.
  for (int kt = 0; kt < 14; ++kt) {
    int curOff = (kt & 1) * BUFSZ, nxtOff = curOff ^ BUFSZ;
    loadAfrags(curOff);
    PRIO1();
    computeJ(curOff, 0);
    computeJ(curOff, 1);
    PRIO0();
    gloadA(nxtOff, kt + 1);  // issue early: full half-iter to land
    writeB(nxtOff);          // B(kt+1) regs aged ~1 iter
    loadB(kt + 2);
    SCHED0();
    PRIO1();
    computeJ(curOff, 2);
    computeJ(curOff, 3);
    PRIO0();
    SCHED0();
    VMCNT(8);
    LGKM0(); SBAR(); SCHED0();
  }
  // kt=14: stage tile 15, no more B loads
  {
    loadAfrags(0);
    PRIO1();
    computeJ(0, 0); computeJ(0, 1);
    PRIO0();
    gloadA(BUFSZ, 15);
    writeB(BUFSZ);
    SCHED0();
    PRIO1();
    computeJ(0, 2); computeJ(0, 3);
    PRIO0();
    SCHED0();
    VMCNT(0);
    LGKM0(); SBAR(); SCHED0();
  }
  // kt=15
  loadAfrags(BUFSZ);
  PRIO1();
  computeJ(BUFSZ, 0); computeJ(BUFSZ, 1);
  computeJ(BUFSZ, 2); computeJ(BUFSZ, 3);
  PRIO0();

  // epilogue: D layout col = lane&15, row = (lane>>4)*4 + r (m89-verified)
  #pragma unroll
  for (int i = 0; i < 4; ++i) {
    #pragma unroll
    for (int j = 0; j < 4; ++j) {
      #pragma unroll
      for (int r = 0; r < 4; ++r) {
        int m = mBase + wm + i * 16 + l4 * 4 + r;
        int o = oBase + wn + j * 16 + l16;
        op[(size_t)m * OROW + n * DO + o] = acc[i][j][r] + bi[j];
      }
    }
  }
}

extern "C" void kernel_launch(void* const* d_in, const int* in_sizes, int n_in,
                              void* d_out, int out_size, void* d_ws, size_t ws_size,
                              hipStream_t stream) {
  const float* x = (const float*)d_in[0];
  const float* w = (const float*)d_in[1];
  const float* b = (const float*)d_in[2];
  float* o = (float*)d_out;
  hipLaunchKernelGGL(nlinear_mfma, dim3(512), dim3(512), 0, stream, x, w, b, o);
}